// Round 10
// baseline (82.478 us; speedup 1.0000x reference)
//
#include <hip/hip_runtime.h>
#include <hip/hip_bf16.h>

#define NUM_CLASSES 200
#define NF 128
#define NP 2000
#define NPC 10          // prototypes per class
#define HW 196
#define MPAD 208        // 13 * 16 hw rows (padded)
#define NCH 13
#define NB 64
#define EPSV 1e-4f
#define TROW 17         // fp32 staging tile row stride (floats)
#define PTILE 500       // protos per block = exactly 50 classes (class-aligned)
#define CTILE 50        // classes per block

typedef __attribute__((ext_vector_type(8))) short short8;   // 8 bf16 = 4 VGPR
typedef __attribute__((ext_vector_type(4))) float f32x4;

static __device__ __forceinline__ unsigned short f2bf(float x) {
    __hip_bfloat16 h = __float2bfloat16(x);
    return __builtin_bit_cast(unsigned short, h);
}

// ---- single fused kernel -----------------------------------------------------
// grid (64 n, 4 class-aligned p-tiles of 500) x 512 threads (8 waves) -> one
// block per CU; linear id = n + 64*pt so the 4 blocks of one n share an XCD
// (f[n] L2-resident after the first reader).
// Phases (all individually verified in earlier rounds):
//   A. A-frags + exact fp32 psq from fp32 protos in registers (R1/R2/R6).
//   B. f[n] transpose fp32->bf16 into XOR-swizzled LDS via the R2-verified
//      two-barrier fp32-tile pipeline, 2 chunks/round x 7 rounds (TROW=17
//      conflict-free tiles); inline exact fp32 xsq -> LDS.
//   C. 13x16 MFMAs/wave, running min (R5/R9 verified swizzled read).
//   D. Epilogue: min reduce, min_out, sim, 50 block-local class sums, logits
//      contribution as 200 atomicAdds (zero-init by hipMemsetAsync; R6-proven).
__global__ __launch_bounds__(512, 2) void kmain(const float* __restrict__ f,
                                                const float* __restrict__ protos,
                                                const float* __restrict__ W,
                                                float* __restrict__ min_out,
                                                float* __restrict__ logits) {
    __shared__ unsigned short sf[MPAD * NF];   // 53,248 B bf16 B-matrix (swizzled)
    __shared__ float tile[2][NF * TROW];       // 17,408 B fp32 staging, 2 chunks
    __shared__ float sxsq[MPAD];               //    832 B
    __shared__ float scsum[64];                //    256 B
    float* const ssim = (float*)sf;            // overlay: sf is dead post-MFMA

    const int n    = blockIdx.x;
    const int pt   = blockIdx.y;
    const int t    = threadIdx.x;
    const int wave = t >> 6;
    const int lane = t & 63;
    const int row  = lane & 15;
    const int quad = lane >> 4;
    const int sb   = wave * 64;                // slot base within block (0..511)
    const int p0   = pt * PTILE;               // first proto of this block

    // ---- A. proto A-frags (cvt bf16) + exact fp32 psq ------------------------
    // slot = sb + g*16 + row; proto p = p0 + slot (clamped; masked in epilogue)
    short8 A[4][4];
    float psum[4];
    #pragma unroll
    for (int g = 0; g < 4; ++g) {
        int p = p0 + sb + g * 16 + row;
        const float* ap = protos + (size_t)(p < NP ? p : NP - 1) * NF + quad * 8;
        psum[g] = 0.f;
        #pragma unroll
        for (int kk = 0; kk < 4; ++kk) {
            float4 w0 = *(const float4*)(ap + kk * 32);
            float4 w1 = *(const float4*)(ap + kk * 32 + 4);
            psum[g] += w0.x * w0.x + w0.y * w0.y + w0.z * w0.z + w0.w * w0.w
                     + w1.x * w1.x + w1.y * w1.y + w1.z * w1.z + w1.w * w1.w;
            short8 a;
            a[0] = (short)f2bf(w0.x); a[1] = (short)f2bf(w0.y);
            a[2] = (short)f2bf(w0.z); a[3] = (short)f2bf(w0.w);
            a[4] = (short)f2bf(w1.x); a[5] = (short)f2bf(w1.y);
            a[6] = (short)f2bf(w1.z); a[7] = (short)f2bf(w1.w);
            A[g][kk] = a;
        }
        // sum over the 4 quads -> every lane holds psq of its slot's proto
        psum[g] += __shfl_xor(psum[g], 16, 64);
        psum[g] += __shfl_xor(psum[g], 32, 64);
    }

    // ---- B. f[n] -> bf16 swizzled LDS: 2 chunks/round x 7 rounds -------------
    const int tl   = t & 255;
    const int ch   = t >> 8;          // 0 or 1: which chunk this half handles
    const int kb   = tl >> 2;         // 0..63   (load phase: k row)
    const int hwl  = (tl & 3) * 4;    // 0,4,8,12 (load phase: hw within chunk)
    const int hwl2 = tl >> 4;         // 0..15   (transpose phase: hw row)
    const int kg   = tl & 15;         // 0..15   (transpose phase: 8-k group)

    for (int rd = 0; rd < 7; ++rd) {
        const int mt  = rd * 2 + ch;          // 0..13 (13 = idle half-round)
        const int hw0 = mt * 16;
        float4 v0 = make_float4(0.f, 0.f, 0.f, 0.f), v1 = v0;
        if (mt < NCH && hw0 + hwl + 4 <= HW) {
            v0 = *(const float4*)(f + ((size_t)n * NF + kb) * HW + hw0 + hwl);
            v1 = *(const float4*)(f + ((size_t)n * NF + kb + 64) * HW + hw0 + hwl);
        }
        __syncthreads();   // previous round's tile readers are done
        if (mt < NCH) {
            tile[ch][kb * TROW + hwl + 0] = v0.x;
            tile[ch][kb * TROW + hwl + 1] = v0.y;
            tile[ch][kb * TROW + hwl + 2] = v0.z;
            tile[ch][kb * TROW + hwl + 3] = v0.w;
            tile[ch][(kb + 64) * TROW + hwl + 0] = v1.x;
            tile[ch][(kb + 64) * TROW + hwl + 1] = v1.y;
            tile[ch][(kb + 64) * TROW + hwl + 2] = v1.z;
            tile[ch][(kb + 64) * TROW + hwl + 3] = v1.w;
        }
        __syncthreads();
        if (mt < NCH) {
            // transpose-read column hwl2, k = kg*8..+8; cvt; square-sum
            float xp = 0.f;
            unsigned short u[8];
            #pragma unroll
            for (int j = 0; j < 8; ++j) {
                float val = tile[ch][(kg * 8 + j) * TROW + hwl2];
                xp += val * val;
                u[j] = f2bf(val);
            }
            // XOR-swizzled 16B-unit store: unit kg of row (hw0+hwl2) at kg^hwl2
            ((uint4*)sf)[(hw0 + hwl2) * 16 + (kg ^ hwl2)] = *(uint4*)u;
            // xsq: butterfly over the 16 consecutive lanes sharing hwl2
            xp += __shfl_xor(xp, 1, 64);
            xp += __shfl_xor(xp, 2, 64);
            xp += __shfl_xor(xp, 4, 64);
            xp += __shfl_xor(xp, 8, 64);
            if (kg == 0) sxsq[hw0 + hwl2] = (hw0 + hwl2 < HW) ? xp : 3.0e38f;
        }
    }
    __syncthreads();   // last round's sf/sxsq writes visible to all waves

    // ---- C. MFMA loop (verified swizzled-read pattern) -----------------------
    float runmin[4][4];
    #pragma unroll
    for (int g = 0; g < 4; ++g)
        #pragma unroll
        for (int r = 0; r < 4; ++r) runmin[g][r] = 3.0e38f;

    const short8* sfv = (const short8*)sf;   // 16 units per row
    for (int mt = 0; mt < NCH; ++mt) {
        const int base = (mt * 16 + row) * 16;
        short8 b0 = sfv[base + ((quad + 0)  ^ row)];
        short8 b1 = sfv[base + ((quad + 4)  ^ row)];
        short8 b2 = sfv[base + ((quad + 8)  ^ row)];
        short8 b3 = sfv[base + ((quad + 12) ^ row)];
        float xv = sxsq[mt * 16 + row];

        #pragma unroll
        for (int g = 0; g < 4; ++g) {
            f32x4 acc = {0.f, 0.f, 0.f, 0.f};
            acc = __builtin_amdgcn_mfma_f32_16x16x32_bf16(A[g][0], b0, acc, 0, 0, 0);
            acc = __builtin_amdgcn_mfma_f32_16x16x32_bf16(A[g][1], b1, acc, 0, 0, 0);
            acc = __builtin_amdgcn_mfma_f32_16x16x32_bf16(A[g][2], b2, acc, 0, 0, 0);
            acc = __builtin_amdgcn_mfma_f32_16x16x32_bf16(A[g][3], b3, acc, 0, 0, 0);
            #pragma unroll
            for (int r = 0; r < 4; ++r)
                runmin[g][r] = fminf(runmin[g][r], xv - 2.f * acc[r]);
        }
    }

    __syncthreads();   // all waves done READING sf -> safe to overlay ssim

    // ---- D. min over the 16 D-columns, sim -----------------------------------
    #pragma unroll
    for (int g = 0; g < 4; ++g) {
        #pragma unroll
        for (int off = 1; off < 16; off <<= 1)
            #pragma unroll
            for (int r = 0; r < 4; ++r)
                runmin[g][r] = fminf(runmin[g][r], __shfl_xor(runmin[g][r], off, 64));
        #pragma unroll
        for (int r = 0; r < 4; ++r) {
            // psq for slot sb + g*16 + quad*4 + r lives at lane 20*quad + r
            float psq_sel = __shfl(psum[g], 20 * quad + r, 64);
            int slot = sb + g * 16 + quad * 4 + r;
            if (row == 0) {
                float sim = 0.f;
                if (slot < PTILE) {
                    float m = fmaxf(runmin[g][r] + psq_sel, 0.f);
                    min_out[(size_t)n * NP + p0 + slot] = m;
                    sim = logf((m + 1.f) / (m + EPSV));
                }
                ssim[slot] = sim;
            }
        }
    }
    __syncthreads();

    // ---- block-local class sums (tile = exactly 50 classes) ------------------
    if (t < CTILE) {
        float s = 0.f;
        #pragma unroll
        for (int j = 0; j < NPC; ++j) s += ssim[t * NPC + j];
        scsum[t] = s;
    }
    __syncthreads();

    // ---- logits contribution: 200 atomicAdds, pure accumulation --------------
    if (t < NUM_CLASSES) {
        const float a = W[0];      // correct-class weight   (1.0)
        const float b = W[NPC];    // incorrect-class weight (-0.5)
        float tp = 0.f;
        #pragma unroll
        for (int j = 0; j < CTILE; ++j) tp += scsum[j];   // LDS broadcast reads
        float v = b * tp;
        const int c0 = pt * CTILE;
        if (t >= c0 && t < c0 + CTILE) v += (a - b) * scsum[t - c0];
        atomicAdd(&logits[(size_t)n * NUM_CLASSES + t], v);
    }
}

extern "C" void kernel_launch(void* const* d_in, const int* in_sizes, int n_in,
                              void* d_out, int out_size, void* d_ws, size_t ws_size,
                              hipStream_t stream) {
    const float* f      = (const float*)d_in[0];  // 64x128x14x14
    const float* protos = (const float*)d_in[1];  // 2000x128
    const float* W      = (const float*)d_in[2];  // 200x2000

    float* logits   = (float*)d_out;
    float* min_dist = (float*)d_out + NB * NUM_CLASSES;

    (void)d_ws; (void)ws_size;

    hipMemsetAsync(logits, 0, (size_t)NB * NUM_CLASSES * sizeof(float), stream);
    kmain<<<dim3(NB, 4), 512, 0, stream>>>(f, protos, W, min_dist, logits);
}

// Round 12
// 79.710 us; speedup vs baseline: 1.0347x; 1.0347x over previous
//
#include <hip/hip_runtime.h>
#include <hip/hip_bf16.h>

#define NUM_CLASSES 200
#define NF 128
#define NP 2000
#define NPC 10          // prototypes per class
#define HW 196
#define MPAD 208        // 13 * 16 hw rows (padded)
#define NCH 13
#define NB 64
#define EPSV 1e-4f
#define PTILE 500       // protos per block = exactly 50 classes (class-aligned)
#define CTILE 50        // classes per block

typedef __attribute__((ext_vector_type(8))) short short8;   // 8 bf16 = 4 VGPR
typedef __attribute__((ext_vector_type(4))) float f32x4;

static __device__ __forceinline__ unsigned short f2bf(float x) {
    __hip_bfloat16 h = __float2bfloat16(x);
    return __builtin_bit_cast(unsigned short, h);
}

// ---- single fused kernel -----------------------------------------------------
// grid (64 n, 4 class-aligned p-tiles of 500) x 512 threads (8 waves); linear
// block id = n + 64*pt -> the 4 blocks of one n share an XCD (f[n] L2-shared).
// Phases:
//   B. BARRIER-FREE gather-transpose staging: thread (kg=t>>5, rp=t&31) reads
//      8 x float2 of f[n] at k-stride (32 lanes = 256B contiguous per (kg,j)),
//      cvt in regs, writes TWO uint4 units into sf at the kprep-proven swizzle
//      position hw*16 + (kg^(hw&15)) -- identical layout to the verified G
//      path, so the MFMA read side is unchanged. Exact fp32 xsq partials into
//      swp[kg][hw] (mild write aliasing only). No barriers in staging (vs 14
//      in R10 -- the identified fusion killer), 2 barriers total before MFMA.
//   A. A-frags + exact fp32 psq from fp32 protos in registers (R1/R10 proven).
//   C. 13x16 MFMAs/wave, running min (R5/R9/R10 verified swizzled read).
//   D. Epilogue: min reduce, min_out, sim, 50 block-local class sums, logits
//      contribution as 200 atomicAdds (zero-init by hipMemsetAsync; proven).
__global__ __launch_bounds__(512, 2) void kmain(const float* __restrict__ f,
                                                const float* __restrict__ protos,
                                                const float* __restrict__ W,
                                                float* __restrict__ min_out,
                                                float* __restrict__ logits) {
    __shared__ unsigned short sf[MPAD * NF];   // 53,248 B bf16 B-matrix (swizzled)
    __shared__ float swp[16 * MPAD];           // 13,312 B xsq partials [kg][hw]
    __shared__ float sxsq[MPAD];               //    832 B
    __shared__ float scsum[64];                //    256 B
    float* const ssim = (float*)sf;            // overlay: sf is dead post-MFMA

    const int n    = blockIdx.x;
    const int pt   = blockIdx.y;
    const int t    = threadIdx.x;
    const int wave = t >> 6;
    const int lane = t & 63;
    const int row  = lane & 15;
    const int quad = lane >> 4;
    const int sb   = wave * 64;                // slot base within block (0..511)
    const int p0   = pt * PTILE;               // first proto of this block

    // ---- B. gather-transpose staging: 4 rounds, no barriers ------------------
    // thread owns units (hw, kg) and (hw+1, kg): 8 k-values each, k = kg*8+j
    const int kg = t >> 5;       // 0..15 (16B unit / 8-k group)
    const int rp = t & 31;       // 0..31 (row-pair within round)
    const float* fkg = f + ((size_t)n * NF + kg * 8) * HW;
    #pragma unroll
    for (int rd = 0; rd < 4; ++rd) {
        const int hw = rd * 64 + rp * 2;       // even; covers hw, hw+1
        float2 v[8];
        if (hw + 2 <= HW) {
            #pragma unroll
            for (int j = 0; j < 8; ++j)
                v[j] = *(const float2*)(fkg + j * HW + hw);   // 256B/32-lane coalesced
        } else {
            #pragma unroll
            for (int j = 0; j < 8; ++j) v[j] = make_float2(0.f, 0.f);
        }
        if (hw < MPAD) {
            unsigned short u0[8], u1[8];
            float s0 = 0.f, s1 = 0.f;
            #pragma unroll
            for (int j = 0; j < 8; ++j) {
                s0 += v[j].x * v[j].x;  s1 += v[j].y * v[j].y;
                u0[j] = f2bf(v[j].x);   u1[j] = f2bf(v[j].y);
            }
            // proven swizzle formula (kprep's G store, target = LDS)
            ((uint4*)sf)[hw * 16       + (kg ^ (hw & 15))]       = *(uint4*)u0;
            ((uint4*)sf)[(hw + 1) * 16 + (kg ^ ((hw + 1) & 15))] = *(uint4*)u1;
            swp[kg * MPAD + hw]     = s0;
            swp[kg * MPAD + hw + 1] = s1;
        }
    }

    // ---- A. proto A-frags (cvt bf16) + exact fp32 psq ------------------------
    // slot = sb + g*16 + row; proto p = p0 + slot (clamped; masked in epilogue)
    short8 A[4][4];
    float psum[4];
    #pragma unroll
    for (int g = 0; g < 4; ++g) {
        int p = p0 + sb + g * 16 + row;
        const float* ap = protos + (size_t)(p < NP ? p : NP - 1) * NF + quad * 8;
        psum[g] = 0.f;
        #pragma unroll
        for (int kk = 0; kk < 4; ++kk) {
            float4 w0 = *(const float4*)(ap + kk * 32);
            float4 w1 = *(const float4*)(ap + kk * 32 + 4);
            psum[g] += w0.x * w0.x + w0.y * w0.y + w0.z * w0.z + w0.w * w0.w
                     + w1.x * w1.x + w1.y * w1.y + w1.z * w1.z + w1.w * w1.w;
            short8 a;
            a[0] = (short)f2bf(w0.x); a[1] = (short)f2bf(w0.y);
            a[2] = (short)f2bf(w0.z); a[3] = (short)f2bf(w0.w);
            a[4] = (short)f2bf(w1.x); a[5] = (short)f2bf(w1.y);
            a[6] = (short)f2bf(w1.z); a[7] = (short)f2bf(w1.w);
            A[g][kk] = a;
        }
        // sum over the 4 quads -> every lane holds psq of its slot's proto
        psum[g] += __shfl_xor(psum[g], 16, 64);
        psum[g] += __shfl_xor(psum[g], 32, 64);
    }

    __syncthreads();   // staging (sf, swp) complete across all waves

    // ---- xsq finalize: sum the 16 kg-partials per hw row ---------------------
    if (t < MPAD) {
        float s = 0.f;
        #pragma unroll
        for (int g16 = 0; g16 < 16; ++g16) s += swp[g16 * MPAD + t];
        sxsq[t] = (t < HW) ? s : 3.0e38f;
    }
    __syncthreads();

    // ---- C. MFMA loop (verified swizzled-read pattern) -----------------------
    float runmin[4][4];
    #pragma unroll
    for (int g = 0; g < 4; ++g)
        #pragma unroll
        for (int r = 0; r < 4; ++r) runmin[g][r] = 3.0e38f;

    const short8* sfv = (const short8*)sf;   // 16 units per row
    for (int mt = 0; mt < NCH; ++mt) {
        const int base = (mt * 16 + row) * 16;
        short8 b0 = sfv[base + ((quad + 0)  ^ row)];
        short8 b1 = sfv[base + ((quad + 4)  ^ row)];
        short8 b2 = sfv[base + ((quad + 8)  ^ row)];
        short8 b3 = sfv[base + ((quad + 12) ^ row)];
        float xv = sxsq[mt * 16 + row];

        #pragma unroll
        for (int g = 0; g < 4; ++g) {
            f32x4 acc = {0.f, 0.f, 0.f, 0.f};
            acc = __builtin_amdgcn_mfma_f32_16x16x32_bf16(A[g][0], b0, acc, 0, 0, 0);
            acc = __builtin_amdgcn_mfma_f32_16x16x32_bf16(A[g][1], b1, acc, 0, 0, 0);
            acc = __builtin_amdgcn_mfma_f32_16x16x32_bf16(A[g][2], b2, acc, 0, 0, 0);
            acc = __builtin_amdgcn_mfma_f32_16x16x32_bf16(A[g][3], b3, acc, 0, 0, 0);
            #pragma unroll
            for (int r = 0; r < 4; ++r)
                runmin[g][r] = fminf(runmin[g][r], xv - 2.f * acc[r]);
        }
    }

    __syncthreads();   // all waves done READING sf -> safe to overlay ssim

    // ---- D. min over the 16 D-columns, sim -----------------------------------
    #pragma unroll
    for (int g = 0; g < 4; ++g) {
        #pragma unroll
        for (int off = 1; off < 16; off <<= 1)
            #pragma unroll
            for (int r = 0; r < 4; ++r)
                runmin[g][r] = fminf(runmin[g][r], __shfl_xor(runmin[g][r], off, 64));
        #pragma unroll
        for (int r = 0; r < 4; ++r) {
            // psq for slot sb + g*16 + quad*4 + r lives at lane 20*quad + r
            float psq_sel = __shfl(psum[g], 20 * quad + r, 64);
            int slot = sb + g * 16 + quad * 4 + r;
            if (row == 0) {
                float sim = 0.f;
                if (slot < PTILE) {
                    float m = fmaxf(runmin[g][r] + psq_sel, 0.f);
                    min_out[(size_t)n * NP + p0 + slot] = m;
                    sim = logf((m + 1.f) / (m + EPSV));
                }
                ssim[slot] = sim;
            }
        }
    }
    __syncthreads();

    // ---- block-local class sums (tile = exactly 50 classes) ------------------
    if (t < CTILE) {
        float s = 0.f;
        #pragma unroll
        for (int j = 0; j < NPC; ++j) s += ssim[t * NPC + j];
        scsum[t] = s;
    }
    __syncthreads();

    // ---- logits contribution: 200 atomicAdds, pure accumulation --------------
    if (t < NUM_CLASSES) {
        const float a = W[0];      // correct-class weight   (1.0)
        const float b = W[NPC];    // incorrect-class weight (-0.5)
        float tp = 0.f;
        #pragma unroll
        for (int j = 0; j < CTILE; ++j) tp += scsum[j];   // LDS broadcast reads
        float v = b * tp;
        const int c0 = pt * CTILE;
        if (t >= c0 && t < c0 + CTILE) v += (a - b) * scsum[t - c0];
        atomicAdd(&logits[(size_t)n * NUM_CLASSES + t], v);
    }
}

extern "C" void kernel_launch(void* const* d_in, const int* in_sizes, int n_in,
                              void* d_out, int out_size, void* d_ws, size_t ws_size,
                              hipStream_t stream) {
    const float* f      = (const float*)d_in[0];  // 64x128x14x14
    const float* protos = (const float*)d_in[1];  // 2000x128
    const float* W      = (const float*)d_in[2];  // 200x2000

    float* logits   = (float*)d_out;
    float* min_dist = (float*)d_out + NB * NUM_CLASSES;

    (void)d_ws; (void)ws_size;

    hipMemsetAsync(logits, 0, (size_t)NB * NUM_CLASSES * sizeof(float), stream);
    kmain<<<dim3(NB, 4), 512, 0, stream>>>(f, protos, W, min_dist, logits);
}

// Round 13
// 76.967 us; speedup vs baseline: 1.0716x; 1.0356x over previous
//
#include <hip/hip_runtime.h>
#include <hip/hip_bf16.h>

#define NUM_CLASSES 200
#define NF 128
#define NP 2000
#define NPC 10          // prototypes per class
#define HW 196
#define MPAD 208        // 13 * 16 hw rows (padded)
#define NB 64
#define EPSV 1e-4f
#define TROW 17         // fp32 staging tile row stride (floats)
#define PTILE 500       // protos per block = exactly 50 classes (class-aligned)
#define CTILE 50        // classes per block

typedef __attribute__((ext_vector_type(8))) short short8;   // 8 bf16 = 4 VGPR
typedef __attribute__((ext_vector_type(4))) float f32x4;

static __device__ __forceinline__ unsigned short f2bf(float x) {
    __hip_bfloat16 h = __float2bfloat16(x);
    return __builtin_bit_cast(unsigned short, h);
}

// async global->LDS staging, 16B/lane and 4B/lane variants (size must be literal)
static __device__ __forceinline__ void gl_lds16(const void* g, void* l) {
    __builtin_amdgcn_global_load_lds(
        (const __attribute__((address_space(1))) void*)g,
        (__attribute__((address_space(3))) void*)l, 16, 0, 0);
}
static __device__ __forceinline__ void gl_lds4(const void* g, void* l) {
    __builtin_amdgcn_global_load_lds(
        (const __attribute__((address_space(1))) void*)g,
        (__attribute__((address_space(3))) void*)l, 4, 0, 0);
}

// ---- kernel 0: once-per-n transpose/cvt prep + proto precompute --------------
// (byte-identical to the verified 76.8us round-9 version)
// grid (64 n, 14). mt<13: transpose one 16-hw x 128-k fp32 chunk of f[n] into
// bf16, stored to G pre-XOR-swizzled in 16B units (unit kg of row hw at
// position kg ^ (hw & 15)) so kdist can global_load_lds LINEARLY and read with
// the swizzled MFMA pattern; plus exact fp32 xsq per hw row.
// mt==0 zero-inits the logits accumulator row (plain store, ordered before
// kdist's atomics by stream dispatch order). mt==13: block n converts protos
// [n*32, n*32+32) to bf16 (pB) + exact fp32 psq (psqG).
__global__ __launch_bounds__(256) void kprep(const float* __restrict__ f,
                                             const float* __restrict__ protos,
                                             uint4* __restrict__ G,
                                             float* __restrict__ xsqG,
                                             unsigned short* __restrict__ pB,
                                             float* __restrict__ psqG,
                                             float* __restrict__ logits) {
    __shared__ float tile[NF * TROW];   // 8,704 B fp32 staging [k][hw_local]

    const int n  = blockIdx.x;
    const int mt = blockIdx.y;
    const int t  = threadIdx.x;

    if (mt == 13) {
        // ---- proto precompute: 32 rows per block, 8 lanes per row ------------
        const int rl  = t >> 3;          // 0..31 local row
        const int sub = t & 7;           // 16-col segment
        const int p   = n * 32 + rl;
        if (p < NP) {
            const float* pr = protos + (size_t)p * NF + sub * 16;
            float xp = 0.f;
            unsigned short u[16];
            #pragma unroll
            for (int q = 0; q < 4; ++q) {
                float4 v = *(const float4*)(pr + q * 4);
                xp += v.x * v.x + v.y * v.y + v.z * v.z + v.w * v.w;
                u[q * 4 + 0] = f2bf(v.x); u[q * 4 + 1] = f2bf(v.y);
                u[q * 4 + 2] = f2bf(v.z); u[q * 4 + 3] = f2bf(v.w);
            }
            uint4* dst = (uint4*)(pB + (size_t)p * NF + sub * 16);
            dst[0] = ((uint4*)u)[0];
            dst[1] = ((uint4*)u)[1];
            // exact psq: butterfly over the 8 lanes of this row (t = rl*8+sub)
            xp += __shfl_xor(xp, 1, 64);
            xp += __shfl_xor(xp, 2, 64);
            xp += __shfl_xor(xp, 4, 64);
            if (sub == 0) psqG[p] = xp;
        }
        return;
    }

    if (mt == 0 && t < NUM_CLASSES) logits[(size_t)n * NUM_CLASSES + t] = 0.f;

    const int hw0 = mt * 16;
    // load phase: k row = t>>2 (and +64), 4 hw values at (t&3)*4
    const int kb  = t >> 2;
    const int hwl = (t & 3) * 4;
    float4 v0 = make_float4(0.f, 0.f, 0.f, 0.f), v1 = v0;
    if (hw0 + hwl + 4 <= HW) {
        v0 = *(const float4*)(f + ((size_t)n * NF + kb) * HW + hw0 + hwl);
        v1 = *(const float4*)(f + ((size_t)n * NF + kb + 64) * HW + hw0 + hwl);
    }
    tile[kb * TROW + hwl + 0] = v0.x;
    tile[kb * TROW + hwl + 1] = v0.y;
    tile[kb * TROW + hwl + 2] = v0.z;
    tile[kb * TROW + hwl + 3] = v0.w;
    tile[(kb + 64) * TROW + hwl + 0] = v1.x;
    tile[(kb + 64) * TROW + hwl + 1] = v1.y;
    tile[(kb + 64) * TROW + hwl + 2] = v1.z;
    tile[(kb + 64) * TROW + hwl + 3] = v1.w;
    __syncthreads();

    // transpose phase: hw row = t>>4, 8-k group = t&15; cvt + exact xsq
    const int hwl2 = t >> 4;
    const int kg   = t & 15;
    float xp = 0.f;
    unsigned short u[8];
    #pragma unroll
    for (int j = 0; j < 8; ++j) {
        float val = tile[(kg * 8 + j) * TROW + hwl2];
        xp += val * val;
        u[j] = f2bf(val);
    }
    // pre-swizzled global store: 1KB contiguous per wave (permuted within rows)
    G[((size_t)n * MPAD + hw0 + hwl2) * 16 + (kg ^ hwl2)] = *(uint4*)u;

    // xsq: butterfly over the 16 consecutive lanes sharing hwl2
    xp += __shfl_xor(xp, 1, 64);
    xp += __shfl_xor(xp, 2, 64);
    xp += __shfl_xor(xp, 4, 64);
    xp += __shfl_xor(xp, 8, 64);
    if (kg == 0) xsqG[(size_t)n * 256 + hw0 + hwl2] = (hw0 + hwl2 < HW) ? xp : 3.0e38f;
}

// ---- kernel 1: distance kernel, 512-thread consolidated blocks ---------------
// grid (64 n, 4 class-aligned p-tiles of 500) x 512 threads (8 waves) -> ONE
// block per CU, single round. Verified dataflow: 7x global_load_lds iterations
// (linear dest == pre-swizzled G), ONE barrier before MFMA; A-frags direct
// bf16 from pB; per-wave 13x16 MFMAs; epilogue: min reduce, min_out, sim, 50
// block-local class sums, logits contribution as 200 atomicAdds.
__global__ __launch_bounds__(512, 2) void kdist(const uint4* __restrict__ G,
                                                const float* __restrict__ xsqG,
                                                const unsigned short* __restrict__ pB,
                                                const float* __restrict__ psqG,
                                                const float* __restrict__ W,
                                                float* __restrict__ min_out,
                                                float* __restrict__ logits) {
    __shared__ unsigned short sf[MPAD * NF];   // 53,248 B bf16 B-matrix (swizzled)
    __shared__ float sxsq[256];                //  1,024 B
    __shared__ float scsum[64];                //    256 B
    float* const ssim = (float*)sf;            // overlay: sf is dead post-MFMA

    const int n    = blockIdx.x;
    const int pt   = blockIdx.y;
    const int t    = threadIdx.x;
    const int wave = t >> 6;
    const int lane = t & 63;
    const int row  = lane & 15;
    const int quad = lane >> 4;
    const int sb   = wave * 64;                // slot base within block (0..511)
    const int p0   = pt * PTILE;               // first proto of this block

    // ---- issue B staging first: 7 iterations x (512 lanes x 16B) + xsq -------
    // total units = 13*256 = 3328 = 6*512 + 256 (iteration 6: waves 0-3 only)
    if (t < 256)
        gl_lds4(xsqG + (size_t)n * 256 + t, (char*)sxsq + (size_t)wave * 64 * 4);
    const uint4* gsrc = G + (size_t)n * (MPAD * 16);
    #pragma unroll
    for (int i = 0; i < 7; ++i) {
        if (i < 6 || t < 256)   // whole waves active or inactive
            gl_lds16(gsrc + i * 512 + t,
                     (char*)sf + ((size_t)i * 512 + wave * 64) * 16);
    }

    // ---- A frags: direct bf16 loads (precomputed in kprep) -------------------
    // slot = sb + g*16 + row; proto p = p0 + slot (clamped; masked in epilogue)
    short8 A[4][4];
    #pragma unroll
    for (int g = 0; g < 4; ++g) {
        int p = p0 + sb + g * 16 + row;
        const short8* pr = (const short8*)(pB + (size_t)(p < NP ? p : NP - 1) * NF);
        #pragma unroll
        for (int kk = 0; kk < 4; ++kk)
            A[g][kk] = pr[quad + kk * 4];   // shorts [quad*8 + kk*32, +8)
    }

    __syncthreads();   // staging complete (vmcnt(0) drain) across all waves

    // ---- MFMA loop (verified swizzled-read pattern) --------------------------
    float runmin[4][4];
    #pragma unroll
    for (int g = 0; g < 4; ++g)
        #pragma unroll
        for (int r = 0; r < 4; ++r) runmin[g][r] = 3.0e38f;

    const short8* sfv = (const short8*)sf;   // 16 units per row
    for (int mt = 0; mt < 13; ++mt) {
        const int base = (mt * 16 + row) * 16;
        short8 b0 = sfv[base + ((quad + 0)  ^ row)];
        short8 b1 = sfv[base + ((quad + 4)  ^ row)];
        short8 b2 = sfv[base + ((quad + 8)  ^ row)];
        short8 b3 = sfv[base + ((quad + 12) ^ row)];
        float xv = sxsq[mt * 16 + row];

        #pragma unroll
        for (int g = 0; g < 4; ++g) {
            f32x4 acc = {0.f, 0.f, 0.f, 0.f};
            acc = __builtin_amdgcn_mfma_f32_16x16x32_bf16(A[g][0], b0, acc, 0, 0, 0);
            acc = __builtin_amdgcn_mfma_f32_16x16x32_bf16(A[g][1], b1, acc, 0, 0, 0);
            acc = __builtin_amdgcn_mfma_f32_16x16x32_bf16(A[g][2], b2, acc, 0, 0, 0);
            acc = __builtin_amdgcn_mfma_f32_16x16x32_bf16(A[g][3], b3, acc, 0, 0, 0);
            #pragma unroll
            for (int r = 0; r < 4; ++r)
                runmin[g][r] = fminf(runmin[g][r], xv - 2.f * acc[r]);
        }
    }

    __syncthreads();   // all waves done READING sf -> safe to overlay ssim

    // ---- min over the 16 D-columns, sim --------------------------------------
    #pragma unroll
    for (int g = 0; g < 4; ++g) {
        #pragma unroll
        for (int off = 1; off < 16; off <<= 1)
            #pragma unroll
            for (int r = 0; r < 4; ++r)
                runmin[g][r] = fminf(runmin[g][r], __shfl_xor(runmin[g][r], off, 64));
        #pragma unroll
        for (int r = 0; r < 4; ++r) {
            int slot = sb + g * 16 + quad * 4 + r;
            if (row == 0) {
                float sim = 0.f;
                if (slot < PTILE) {
                    float m = fmaxf(runmin[g][r] + psqG[p0 + slot], 0.f);
                    min_out[(size_t)n * NP + p0 + slot] = m;
                    sim = logf((m + 1.f) / (m + EPSV));
                }
                ssim[slot] = sim;
            }
        }
    }
    __syncthreads();

    // ---- block-local class sums (tile = exactly 50 classes) ------------------
    if (t < CTILE) {
        float s = 0.f;
        #pragma unroll
        for (int j = 0; j < NPC; ++j) s += ssim[t * NPC + j];
        scsum[t] = s;
    }
    __syncthreads();

    // ---- logits contribution: 200 atomicAdds, pure accumulation --------------
    if (t < NUM_CLASSES) {
        const float a = W[0];      // correct-class weight   (1.0)
        const float b = W[NPC];    // incorrect-class weight (-0.5)
        float tp = 0.f;
        #pragma unroll
        for (int j = 0; j < CTILE; ++j) tp += scsum[j];   // LDS broadcast reads
        float v = b * tp;
        const int c0 = pt * CTILE;
        if (t >= c0 && t < c0 + CTILE) v += (a - b) * scsum[t - c0];
        atomicAdd(&logits[(size_t)n * NUM_CLASSES + t], v);
    }
}

extern "C" void kernel_launch(void* const* d_in, const int* in_sizes, int n_in,
                              void* d_out, int out_size, void* d_ws, size_t ws_size,
                              hipStream_t stream) {
    const float* f      = (const float*)d_in[0];  // 64x128x14x14
    const float* protos = (const float*)d_in[1];  // 2000x128
    const float* W      = (const float*)d_in[2];  // 200x2000

    float* logits   = (float*)d_out;
    float* min_dist = (float*)d_out + NB * NUM_CLASSES;

    // workspace layout:
    //   [0, 512000)          pB    bf16 protos 2000x128
    //   [512000, 520000)     psqG  f32 2000
    //   [524288, +3407872)   G     bf16 [64][208 rows][16 units][16B], swizzled
    //   then                 xsqG  f32 [64][256]
    unsigned short* pB = (unsigned short*)d_ws;
    float* psqG = (float*)((char*)d_ws + 512000);
    uint4* G    = (uint4*)((char*)d_ws + 524288);
    float* xsqG = (float*)((char*)d_ws + 524288 + (size_t)NB * MPAD * 16 * sizeof(uint4));

    kprep<<<dim3(NB, 14), 256, 0, stream>>>(f, protos, G, xsqG, pB, psqG, logits);
    kdist<<<dim3(NB, 4), 512, 0, stream>>>(G, xsqG, pB, psqG, W, min_dist, logits);
}